// Round 16
// baseline (138.589 us; speedup 1.0000x reference)
//
#include <hip/hip_runtime.h>
#include <hip/hip_bf16.h>

#define B_ 8
#define T_ 2048
#define E_ 1024
#define H_ 64

typedef __attribute__((ext_vector_type(8))) short short8v;
typedef __attribute__((ext_vector_type(4))) float f32x4;

__device__ __forceinline__ unsigned short bfbits(float f) {
  return __builtin_bit_cast(unsigned short, __float2bfloat16(f));
}

// ---- prep: Wf = fragment-major W (bf16). frag cf in 0..11, kb in 0..31.
// Element (lane l, j): m=cf>>2, col=(cf&3)*16+(l&15), k=kb*32+(l>>4)*8+j.
// Each frag is a contiguous 1KB MFMA B-operand. q-scale folded into m==1.
__global__ __launch_bounds__(256) void prep_wf(
    const float* __restrict__ Wk, const float* __restrict__ Wq,
    const float* __restrict__ Wv, __hip_bfloat16* __restrict__ Wf) {
  const int idx = blockIdx.x * 256 + threadIdx.x;  // 12*32*512 = 196608
  const int f = idx >> 9;
  const int e = idx & 511;
  const int l = e >> 3, j = e & 7;
  const int cf = f >> 5, kb = f & 31;
  const int m = cf >> 2;
  const int c = (cf & 3) * 16 + (l & 15);
  const int k = kb * 32 + (l >> 4) * 8 + j;
  const float* W = (m == 0) ? Wk : (m == 1) ? Wq : Wv;
  float v = W[k * H_ + c];
  if (m == 1) v *= 0.03125f;  // 1024^-0.5
  Wf[idx] = __float2bfloat16(v);
}

// ---- projection: 12288 fully-independent waves, no LDS main loop, no barriers.
// grid 3*1024 x 256thr: block b -> matrix mg=b>>10 (K,Q,V), rowtile b&1023;
// wave w owns cols w*16..+15. Per BK=32 step: 2 x-loads + 1 contiguous 1KB
// Wf frag load + 1 MFMA; 4-slot register ring, distance-3 prefetch.
__global__ __launch_bounds__(256) void proj_mfma(
    const float* __restrict__ x, const __hip_bfloat16* __restrict__ Wf,
    __hip_bfloat16* __restrict__ Qb, __hip_bfloat16* __restrict__ Kb,
    __hip_bfloat16* __restrict__ Vt) {
  __shared__ __hip_bfloat16 rep[4][16][24];
  const int tid = threadIdx.x;
  const int lane = tid & 63;
  const int w = tid >> 6;
  const int r = lane & 15, g = lane >> 4;
  const int mg = blockIdx.x >> 10;       // 0,1,2 = K,Q,V
  const int rt = blockIdx.x & 1023;      // 1024 rowtiles of 16 rows
  const int r0 = rt * 16;
  const int c0 = w * 16;
  const int cf = mg * 4 + w;

  f32x4 acc = (f32x4){0.f, 0.f, 0.f, 0.f};
  const float* xr = x + (size_t)(r0 + r) * E_ + g * 8;
  const __hip_bfloat16* wfb = Wf + ((size_t)cf << 14) + lane * 8;  // cf*32*512

  f32x4 aL[4], aH[4];
  short8v bS[4];
  auto loadA = [&](int s, int kb) {
    aL[s] = *(const f32x4*)(xr + kb * 32);
    aH[s] = *(const f32x4*)(xr + kb * 32 + 4);
  };
  auto loadB = [&](int s, int kb) {
    bS[s] = *(const short8v*)(wfb + (kb << 9));
  };
  auto step = [&](int s) {
    short8v A;
    A[0] = (short)bfbits(aL[s][0]); A[1] = (short)bfbits(aL[s][1]);
    A[2] = (short)bfbits(aL[s][2]); A[3] = (short)bfbits(aL[s][3]);
    A[4] = (short)bfbits(aH[s][0]); A[5] = (short)bfbits(aH[s][1]);
    A[6] = (short)bfbits(aH[s][2]); A[7] = (short)bfbits(aH[s][3]);
    acc = __builtin_amdgcn_mfma_f32_16x16x32_bf16(A, bS[s], acc, 0, 0, 0);
  };

  loadA(0, 0); loadB(0, 0);
  loadA(1, 1); loadB(1, 1);
  loadA(2, 2); loadB(2, 2);
  #pragma unroll
  for (int t = 0; t < 32; ++t) {
    if (t + 3 < 32) { loadA((t + 3) & 3, t + 3); loadB((t + 3) & 3, t + 3); }
    step(t & 3);
  }

  if (mg < 2) {  // K or Q: repack to row-major via per-wave LDS
    __hip_bfloat16* Pout = (mg == 0) ? Kb : Qb;
    __hip_bfloat16* rp = &rep[w][0][0];
    #pragma unroll
    for (int reg = 0; reg < 4; ++reg)
      rp[(g * 4 + reg) * 24 + r] = __float2bfloat16(acc[reg]);
    asm volatile("s_waitcnt lgkmcnt(0)" ::: "memory");
    __builtin_amdgcn_sched_barrier(0);
    if (lane < 32) {
      const int row = lane >> 1, ch = lane & 1;
      *(uint4*)(Pout + (size_t)(r0 + row) * H_ + c0 + ch * 8) =
          *(const uint4*)(rp + row * 24 + ch * 8);
    }
  } else {  // V: direct transposed write Vt[b][h][t]
    const int b = r0 >> 11;
    const int tt = (r0 & 2047) + g * 4;
    ushort4 pk;
    pk.x = bfbits(acc[0]); pk.y = bfbits(acc[1]);
    pk.z = bfbits(acc[2]); pk.w = bfbits(acc[3]);
    *(ushort4*)(Vt + (size_t)(b * 64 + c0 + r) * T_ + tt) = pk;
  }
}

// ---- attention: barrier-free, swapped-QK, 2-way in-block key-split (round-4) ----
__global__ __launch_bounds__(128, 2) void attn_mfma(
    const __hip_bfloat16* __restrict__ Qb, const __hip_bfloat16* __restrict__ Kb,
    const __hip_bfloat16* __restrict__ Vt, float* __restrict__ out) {
  __shared__ __hip_bfloat16 Ps[2][16][72];
  __shared__ float cmb[64][20];
  __shared__ float ml[16][2];
  const int tid = threadIdx.x;
  const int lane = tid & 63;
  const int w = tid >> 6;
  const int r = lane & 15, g = lane >> 4;
  const int blk = blockIdx.x;
  const int b = blk & 7;
  const int i = blk >> 3;  // 0..127
  const int s_ = i >> 5, j_ = i & 31;
  const int qt = (s_ == 0) ? j_ : (s_ == 1) ? (63 - j_) : (s_ == 2) ? (64 + j_) : (127 - j_);
  const int q0 = qt * 16;
  const size_t tb = (size_t)b * T_;
  const int bb = b * 64;

  const short8v qf0 = *(const short8v*)(Qb + (tb + q0 + r) * H_ + g * 8);
  const short8v qf1 = *(const short8v*)(Qb + (tb + q0 + r) * H_ + 32 + g * 8);

  f32x4 o[4];
  #pragma unroll
  for (int k2 = 0; k2 < 4; ++k2) o[k2] = (f32x4){0.f, 0.f, 0.f, 0.f};
  float mrun = -1e30f, lrun = 0.f;

  const int nt = (qt >> 2) + 1;
  const int h_ = (nt + 1) >> 1;
  const int t0 = w ? h_ : 0;
  const int t1 = w ? nt : h_;

  short8v kbA[4][2], kbB[4][2];
  auto loadK = [&](int t, short8v (&kb)[4][2]) {
    #pragma unroll
    for (int kg = 0; kg < 4; ++kg)
      #pragma unroll
      for (int c = 0; c < 2; ++c)
        kb[kg][c] = *(const short8v*)(Kb + (tb + t * 64 + kg * 16 + r) * H_ + c * 32 + g * 8);
  };

  auto body = [&](int t, short8v (&kbU)[4][2], short8v (&kbP)[4][2]) {
    short8v vb[4][2];
    #pragma unroll
    for (int hg = 0; hg < 4; ++hg)
      #pragma unroll
      for (int c = 0; c < 2; ++c)
        vb[hg][c] = *(const short8v*)(
            Vt + (size_t)(bb + hg * 16 + r) * T_ + t * 64 + c * 32 + g * 8);
    if (t + 1 < t1) loadK(t + 1, kbP);

    f32x4 s[4];
    #pragma unroll
    for (int k2 = 0; k2 < 4; ++k2) s[k2] = (f32x4){0.f, 0.f, 0.f, 0.f};
    __builtin_amdgcn_s_setprio(1);
    #pragma unroll
    for (int kg = 0; kg < 4; ++kg) {
      s[kg] = __builtin_amdgcn_mfma_f32_16x16x32_bf16(kbU[kg][0], qf0, s[kg], 0, 0, 0);
      s[kg] = __builtin_amdgcn_mfma_f32_16x16x32_bf16(kbU[kg][1], qf1, s[kg], 0, 0, 0);
    }
    __builtin_amdgcn_s_setprio(0);

    if (t == nt - 1) {
      #pragma unroll
      for (int kg = 0; kg < 4; ++kg)
        #pragma unroll
        for (int reg = 0; reg < 4; ++reg)
          if (t * 64 + kg * 16 + g * 4 + reg > q0 + r) s[kg][reg] = -1e30f;
    }

    float pm = s[0][0];
    #pragma unroll
    for (int kg = 0; kg < 4; ++kg)
      #pragma unroll
      for (int reg = 0; reg < 4; ++reg) pm = fmaxf(pm, s[kg][reg]);
    pm = fmaxf(pm, __shfl_xor(pm, 16));
    pm = fmaxf(pm, __shfl_xor(pm, 32));
    const float nm = fmaxf(mrun, pm);
    const float al = __expf(mrun - nm);
    mrun = nm;
    float p[4][4];
    float rs = 0.f;
    #pragma unroll
    for (int kg = 0; kg < 4; ++kg)
      #pragma unroll
      for (int reg = 0; reg < 4; ++reg) {
        p[kg][reg] = __expf(s[kg][reg] - nm);
        rs += p[kg][reg];
      }
    rs += __shfl_xor(rs, 16);
    rs += __shfl_xor(rs, 32);
    lrun = lrun * al + rs;
    #pragma unroll
    for (int hg = 0; hg < 4; ++hg) o[hg] *= al;

    #pragma unroll
    for (int kg = 0; kg < 4; ++kg) {
      ushort4 u;
      u.x = bfbits(p[kg][0]); u.y = bfbits(p[kg][1]);
      u.z = bfbits(p[kg][2]); u.w = bfbits(p[kg][3]);
      *(ushort4*)&Ps[w][r][kg * 16 + g * 4] = u;
    }
    short8v pf[2];
    pf[0] = *(const short8v*)&Ps[w][r][g * 8];
    pf[1] = *(const short8v*)&Ps[w][r][32 + g * 8];

    __builtin_amdgcn_s_setprio(1);
    #pragma unroll
    for (int c = 0; c < 2; ++c)
      #pragma unroll
      for (int hg = 0; hg < 4; ++hg)
        o[hg] = __builtin_amdgcn_mfma_f32_16x16x32_bf16(vb[hg][c], pf[c], o[hg], 0, 0, 0);
    __builtin_amdgcn_s_setprio(0);
  };

  if (t0 < t1) {
    loadK(t0, kbA);
    int t = t0;
    while (true) {
      body(t, kbA, kbB);
      if (++t >= t1) break;
      body(t, kbB, kbA);
      if (++t >= t1) break;
    }
  }

  if (w == 1) {
    if (g == 0) { ml[r][0] = mrun; ml[r][1] = lrun; }
    #pragma unroll
    for (int hg = 0; hg < 4; ++hg) *(f32x4*)&cmb[lane][hg * 4] = o[hg];
  }
  __syncthreads();
  if (w == 0) {
    const float m1 = ml[r][0], l1 = ml[r][1];
    const float mm = fmaxf(mrun, m1);
    const float sc0 = __expf(mrun - mm), sc1 = __expf(m1 - mm);
    const float inv = 1.f / (lrun * sc0 + l1 * sc1);
    #pragma unroll
    for (int hg = 0; hg < 4; ++hg) {
      const f32x4 o1 = *(const f32x4*)&cmb[lane][hg * 4];
      f32x4 res = (o[hg] * sc0 + o1 * sc1) * inv;
      *(f32x4*)(out + (tb + q0 + r) * H_ + hg * 16 + g * 4) = res;
    }
  }
}

extern "C" void kernel_launch(void* const* d_in, const int* in_sizes, int n_in,
                              void* d_out, int out_size, void* d_ws, size_t ws_size,
                              hipStream_t stream) {
  const float* x  = (const float*)d_in[0];
  const float* Wk = (const float*)d_in[1];
  const float* Wq = (const float*)d_in[2];
  const float* Wv = (const float*)d_in[3];
  float* out = (float*)d_out;

  __hip_bfloat16* Qb = (__hip_bfloat16*)d_ws;
  __hip_bfloat16* Kb = Qb + (size_t)B_ * T_ * H_;
  __hip_bfloat16* Vt = Kb + (size_t)B_ * T_ * H_;   // [B][64][T]
  __hip_bfloat16* Wf = Vt + (size_t)B_ * T_ * H_;   // fragment-major W, 384 KB

  prep_wf<<<(12 * 32 * 512) / 256, 256, 0, stream>>>(Wk, Wq, Wv, Wf);
  proj_mfma<<<3 * 1024, 256, 0, stream>>>(x, Wf, Qb, Kb, Vt);
  attn_mfma<<<B_ * (T_ / 16), 128, 0, stream>>>(Qb, Kb, Vt, out);
}